// Round 1
// baseline (365.412 us; speedup 1.0000x reference)
//
#include <hip/hip_runtime.h>

#define Bsz 8
#define Ssz 128
#define Dsz 512
#define Lsz 512
#define Rsz 50
#define Mrows (Bsz * Ssz)          // 1024
#define SLOT (Mrows * Lsz)         // 524288 floats per ws slot
#define OUTMAT (Bsz * Ssz * Ssz)   // 131072

struct K1Args {
  const float* W1[4];
  const float* b1[4];
};

__device__ __forceinline__ float fast_tanh(float x) {
  // tanh(x) = 1 - 2/(exp(2x)+1); v_exp + v_rcp, abs err ~1e-6, handles +-inf.
  float e = __expf(2.0f * x);
  return 1.0f - 2.0f * __builtin_amdgcn_rcpf(e + 1.0f);
}

// ---------------------------------------------------------------------------
// Kernel 1: left/right projections. side = h*2+r; left (r==0) folds in b1.
// GEMM (1024 x 512) @ (512 x 512), 64x64 tile, 256 thr, 4x4 per thread.
// ---------------------------------------------------------------------------
__global__ __launch_bounds__(256) void gemm_lr(const float* __restrict__ x,
                                               K1Args a,
                                               float* __restrict__ ws) {
  const int side = blockIdx.z;
  const int h = side >> 1, r = side & 1;
  const float* W = a.W1[h] + r * (Dsz * Lsz);
  const float* bias = a.b1[h];
  float* out = ws + side * SLOT;
  const int m0 = blockIdx.y * 64;
  const int n0 = blockIdx.x * 64;
  const int tid = threadIdx.x;
  const int tx = tid & 15, ty = tid >> 4;

  __shared__ float As[16][68];   // [k][m], padded
  __shared__ float Bs[16][64];   // [k][n]

  float acc[4][4] = {};

  for (int kt = 0; kt < Dsz; kt += 16) {
    __syncthreads();
    {
      int m = tid >> 2;
      int k4 = (tid & 3) * 4;
      float4 v = *(const float4*)(x + (m0 + m) * Dsz + kt + k4);
      As[k4 + 0][m] = v.x; As[k4 + 1][m] = v.y;
      As[k4 + 2][m] = v.z; As[k4 + 3][m] = v.w;
    }
    {
      int k = tid >> 4;
      int n4 = tx * 4;
      *(float4*)&Bs[k][n4] = *(const float4*)(W + (kt + k) * Lsz + n0 + n4);
    }
    __syncthreads();
#pragma unroll
    for (int k = 0; k < 16; ++k) {
      float4 av = *(const float4*)&As[k][ty * 4];
      float4 bv = *(const float4*)&Bs[k][tx * 4];
      const float* af = (const float*)&av;
      const float* bf = (const float*)&bv;
#pragma unroll
      for (int i = 0; i < 4; ++i)
#pragma unroll
        for (int j = 0; j < 4; ++j) acc[i][j] += af[i] * bf[j];
    }
  }
  float4 bb = make_float4(0.f, 0.f, 0.f, 0.f);
  if (r == 0) bb = *(const float4*)(bias + n0 + tx * 4);
#pragma unroll
  for (int i = 0; i < 4; ++i) {
    float4 o;
    o.x = acc[i][0] + bb.x; o.y = acc[i][1] + bb.y;
    o.z = acc[i][2] + bb.z; o.w = acc[i][3] + bb.w;
    *(float4*)(out + (m0 + ty * 4 + i) * Lsz + n0 + tx * 4) = o;
  }
}

// ---------------------------------------------------------------------------
// Kernel 2: the three scalar heads (span, h2h, t2t). 16x16 pair tile per wg.
// span computed only for lower-triangle tiles; writes both mirror positions.
// ---------------------------------------------------------------------------
__global__ __launch_bounds__(256) void pair_scalar(
    const float* __restrict__ ws,
    const float* __restrict__ w2a, const float* __restrict__ w2b,
    const float* __restrict__ w2c,
    const float* __restrict__ b2a, const float* __restrict__ b2b,
    const float* __restrict__ b2c,
    float* __restrict__ out) {
  const int b = blockIdx.z;
  const int i0 = blockIdx.y * 16;
  const int j0 = blockIdx.x * 16;
  const int tid = threadIdx.x;
  const int tx = tid & 15;   // j
  const int ty = tid >> 4;   // i
  const bool skip_span = (blockIdx.y < blockIdx.x);  // strictly upper tile

  __shared__ float Ls[16][129];
  __shared__ float Rst[128][17];   // transposed: [l][j]
  __shared__ float w2s[128];

  float acc0 = 0.f, acc1 = 0.f, acc2 = 0.f;
  const float* w2p[3] = {w2a, w2b, w2c};

#pragma unroll
  for (int h = 0; h < 3; ++h) {
    if (h == 0 && skip_span) continue;
    const float* Lb = ws + (h * 2) * SLOT + (b * Ssz + i0) * Lsz;
    const float* Rb = ws + (h * 2 + 1) * SLOT + (b * Ssz + j0) * Lsz;
    const float* w2 = w2p[h];
    float accl = 0.f;
    for (int lc = 0; lc < Lsz; lc += 128) {
      __syncthreads();
      {
        int rr = tid >> 4;
        int c = (tid & 15) * 8;
        float4 v0 = *(const float4*)(Lb + rr * Lsz + lc + c);
        float4 v1 = *(const float4*)(Lb + rr * Lsz + lc + c + 4);
        Ls[rr][c + 0] = v0.x; Ls[rr][c + 1] = v0.y;
        Ls[rr][c + 2] = v0.z; Ls[rr][c + 3] = v0.w;
        Ls[rr][c + 4] = v1.x; Ls[rr][c + 5] = v1.y;
        Ls[rr][c + 6] = v1.z; Ls[rr][c + 7] = v1.w;
        float4 u0 = *(const float4*)(Rb + rr * Lsz + lc + c);
        float4 u1 = *(const float4*)(Rb + rr * Lsz + lc + c + 4);
        Rst[c + 0][rr] = u0.x; Rst[c + 1][rr] = u0.y;
        Rst[c + 2][rr] = u0.z; Rst[c + 3][rr] = u0.w;
        Rst[c + 4][rr] = u1.x; Rst[c + 5][rr] = u1.y;
        Rst[c + 6][rr] = u1.z; Rst[c + 7][rr] = u1.w;
      }
      if (tid < 128) w2s[tid] = w2[lc + tid];
      __syncthreads();
#pragma unroll 16
      for (int l = 0; l < 128; ++l) {
        accl += fast_tanh(Ls[ty][l] + Rst[l][tx]) * w2s[l];
      }
    }
    if (h == 0) acc0 = accl;
    else if (h == 1) acc1 = accl;
    else acc2 = accl;
  }

  const int i = i0 + ty, j = j0 + tx;
  const int base = (b * Ssz + i) * Ssz + j;
  out[OUTMAT + base] = acc1 + b2b[0];
  out[2 * OUTMAT + base] = acc2 + b2c[0];
  if (!skip_span && i >= j) {
    float v = acc0 + b2a[0];
    out[(b * Ssz + i) * Ssz + j] = v;
    out[(b * Ssz + j) * Ssz + i] = v;
  }
}

// ---------------------------------------------------------------------------
// Kernel 3: label head (n_out=50, padded to 64). One wg per (b, i).
// Stage tanh tile Hs[128 j][64 l] in LDS, then register-tiled 4j x 8o GEMM.
// ---------------------------------------------------------------------------
__global__ __launch_bounds__(256) void pair_label(
    const float* __restrict__ ws, const float* __restrict__ W2,
    const float* __restrict__ b2, float* __restrict__ out) {
  const int b = blockIdx.y;
  const int i = blockIdx.x;
  const int tid = threadIdx.x;
  const float* Lrow = ws + 6 * SLOT + (b * Ssz + i) * Lsz;
  const float* Rbase = ws + 7 * SLOT + b * Ssz * Lsz;
  float* out3 = out + 3 * OUTMAT;

  __shared__ float Lls[Lsz];
  __shared__ float Hs[128][68];    // [j][l], 68 pad keeps 16B align
  __shared__ float W2s[64][64];    // [l][o], o zero-padded past 50

  if (tid < 128) ((float4*)Lls)[tid] = ((const float4*)Lrow)[tid];

  float acc[4][8] = {};
  const int jg = tid >> 3;   // 0..31 -> j base jg*4
  const int og = tid & 7;    // 0..7  -> o base og*8

  for (int lc = 0; lc < Lsz; lc += 64) {
    __syncthreads();
    {  // stage W2 chunk (zero-padded)
      int l = tid >> 2;
      int o16 = (tid & 3) * 16;
#pragma unroll
      for (int c = 0; c < 16; ++c) {
        int o = o16 + c;
        W2s[l][o] = (o < Rsz) ? W2[(lc + l) * Rsz + o] : 0.0f;
      }
    }
    {  // compute tanh tile
      const int lo = (tid & 7) * 8;
      const int jb = tid >> 3;
#pragma unroll
      for (int jp = 0; jp < 4; ++jp) {
        int j = jp * 32 + jb;
        const float* rp = Rbase + j * Lsz + lc + lo;
        float4 r0 = *(const float4*)(rp);
        float4 r1 = *(const float4*)(rp + 4);
        float4 h0, h1;
        h0.x = fast_tanh(Lls[lc + lo + 0] + r0.x);
        h0.y = fast_tanh(Lls[lc + lo + 1] + r0.y);
        h0.z = fast_tanh(Lls[lc + lo + 2] + r0.z);
        h0.w = fast_tanh(Lls[lc + lo + 3] + r0.w);
        h1.x = fast_tanh(Lls[lc + lo + 4] + r1.x);
        h1.y = fast_tanh(Lls[lc + lo + 5] + r1.y);
        h1.z = fast_tanh(Lls[lc + lo + 6] + r1.z);
        h1.w = fast_tanh(Lls[lc + lo + 7] + r1.w);
        *(float4*)&Hs[j][lo] = h0;
        *(float4*)&Hs[j][lo + 4] = h1;
      }
    }
    __syncthreads();
#pragma unroll 4
    for (int l4 = 0; l4 < 64; l4 += 4) {
      float4 hv[4];
#pragma unroll
      for (int jj = 0; jj < 4; ++jj)
        hv[jj] = *(const float4*)&Hs[jg * 4 + jj][l4];
#pragma unroll
      for (int c = 0; c < 4; ++c) {
        float4 w0 = *(const float4*)&W2s[l4 + c][og * 8];
        float4 w1 = *(const float4*)&W2s[l4 + c][og * 8 + 4];
#pragma unroll
        for (int jj = 0; jj < 4; ++jj) {
          float hval = ((const float*)&hv[jj])[c];
          acc[jj][0] += hval * w0.x;
          acc[jj][1] += hval * w0.y;
          acc[jj][2] += hval * w0.z;
          acc[jj][3] += hval * w0.w;
          acc[jj][4] += hval * w1.x;
          acc[jj][5] += hval * w1.y;
          acc[jj][6] += hval * w1.z;
          acc[jj][7] += hval * w1.w;
        }
      }
    }
  }
#pragma unroll
  for (int jj = 0; jj < 4; ++jj) {
    int j = jg * 4 + jj;
    long base = ((long)(b * Ssz + i) * Ssz + j) * Rsz;
#pragma unroll
    for (int oo = 0; oo < 8; ++oo) {
      int o = og * 8 + oo;
      if (o < Rsz) out3[base + o] = acc[jj][oo] + b2[o];
    }
  }
}

extern "C" void kernel_launch(void* const* d_in, const int* in_sizes, int n_in,
                              void* d_out, int out_size, void* d_ws,
                              size_t ws_size, hipStream_t stream) {
  (void)in_sizes; (void)n_in; (void)out_size; (void)ws_size;
  const float* x = (const float*)d_in[0];
  K1Args a;
  a.W1[0] = (const float*)d_in[1];  a.b1[0] = (const float*)d_in[2];
  a.W1[1] = (const float*)d_in[5];  a.b1[1] = (const float*)d_in[6];
  a.W1[2] = (const float*)d_in[9];  a.b1[2] = (const float*)d_in[10];
  a.W1[3] = (const float*)d_in[13]; a.b1[3] = (const float*)d_in[14];
  const float* w2a = (const float*)d_in[3];
  const float* b2a = (const float*)d_in[4];
  const float* w2b = (const float*)d_in[7];
  const float* b2b = (const float*)d_in[8];
  const float* w2c = (const float*)d_in[11];
  const float* b2c = (const float*)d_in[12];
  const float* W2l = (const float*)d_in[15];
  const float* b2l = (const float*)d_in[16];
  float* ws = (float*)d_ws;   // 8 slots of 1024x512 fp32 = 16 MB
  float* out = (float*)d_out;

  dim3 g1(Lsz / 64, Mrows / 64, 8);
  gemm_lr<<<g1, 256, 0, stream>>>(x, a, ws);
  dim3 g2(Ssz / 16, Ssz / 16, Bsz);
  pair_scalar<<<g2, 256, 0, stream>>>(ws, w2a, w2b, w2c, b2a, b2b, b2c, out);
  dim3 g3(Ssz, Bsz);
  pair_label<<<g3, 256, 0, stream>>>(ws, W2l, b2l, out);
}

// Round 2
// 302.507 us; speedup vs baseline: 1.2079x; 1.2079x over previous
//
#include <hip/hip_runtime.h>

#define Bsz 8
#define Ssz 128
#define Dsz 512
#define Lsz 512
#define Rsz 50
#define Mrows (Bsz * Ssz)          // 1024
#define SLOT (Mrows * Lsz)         // 524288 floats per ws slot
#define OUTMAT (Bsz * Ssz * Ssz)   // 131072

typedef __attribute__((ext_vector_type(8))) short bf16x8;
typedef __attribute__((ext_vector_type(4))) float f32x4;

struct K1Args {
  const float* W1[4];
  const float* b1[4];
};

__device__ __forceinline__ float fast_tanh(float x) {
  // tanh(x) = 1 - 2/(exp(2x)+1); v_exp + v_rcp, abs err ~1e-6, handles +-inf.
  float e = __expf(2.0f * x);
  return 1.0f - 2.0f * __builtin_amdgcn_rcpf(e + 1.0f);
}

__device__ __forceinline__ short f2bf(float x) {
  // round-to-nearest-even fp32 -> bf16 bits (inputs are finite, |x| bounded)
  union { float f; unsigned u; } v; v.f = x;
  unsigned r = v.u + 0x7FFFu + ((v.u >> 16) & 1u);
  return (short)(r >> 16);
}

// ---------------------------------------------------------------------------
// Kernel 1: left/right projections. side = h*2+r; left (r==0) folds in b1.
// GEMM (1024 x 512) @ (512 x 512), 64x64 tile, 256 thr, 4x4 per thread.
// ---------------------------------------------------------------------------
__global__ __launch_bounds__(256) void gemm_lr(const float* __restrict__ x,
                                               K1Args a,
                                               float* __restrict__ ws) {
  const int side = blockIdx.z;
  const int h = side >> 1, r = side & 1;
  const float* W = a.W1[h] + r * (Dsz * Lsz);
  const float* bias = a.b1[h];
  float* out = ws + side * SLOT;
  const int m0 = blockIdx.y * 64;
  const int n0 = blockIdx.x * 64;
  const int tid = threadIdx.x;
  const int tx = tid & 15, ty = tid >> 4;

  __shared__ float As[16][68];   // [k][m], padded
  __shared__ float Bs[16][64];   // [k][n]

  float acc[4][4] = {};

  for (int kt = 0; kt < Dsz; kt += 16) {
    __syncthreads();
    {
      int m = tid >> 2;
      int k4 = (tid & 3) * 4;
      float4 v = *(const float4*)(x + (m0 + m) * Dsz + kt + k4);
      As[k4 + 0][m] = v.x; As[k4 + 1][m] = v.y;
      As[k4 + 2][m] = v.z; As[k4 + 3][m] = v.w;
    }
    {
      int k = tid >> 4;
      int n4 = tx * 4;
      *(float4*)&Bs[k][n4] = *(const float4*)(W + (kt + k) * Lsz + n0 + n4);
    }
    __syncthreads();
#pragma unroll
    for (int k = 0; k < 16; ++k) {
      float4 av = *(const float4*)&As[k][ty * 4];
      float4 bv = *(const float4*)&Bs[k][tx * 4];
      const float* af = (const float*)&av;
      const float* bf = (const float*)&bv;
#pragma unroll
      for (int i = 0; i < 4; ++i)
#pragma unroll
        for (int j = 0; j < 4; ++j) acc[i][j] += af[i] * bf[j];
    }
  }
  float4 bb = make_float4(0.f, 0.f, 0.f, 0.f);
  if (r == 0) bb = *(const float4*)(bias + n0 + tx * 4);
#pragma unroll
  for (int i = 0; i < 4; ++i) {
    float4 o;
    o.x = acc[i][0] + bb.x; o.y = acc[i][1] + bb.y;
    o.z = acc[i][2] + bb.z; o.w = acc[i][3] + bb.w;
    *(float4*)(out + (m0 + ty * 4 + i) * Lsz + n0 + tx * 4) = o;
  }
}

// ---------------------------------------------------------------------------
// Kernel 2: the three scalar heads (span, h2h, t2t). 16x16 pair tile per wg.
// span computed only for lower-triangle tiles; writes both mirror positions.
// ---------------------------------------------------------------------------
__global__ __launch_bounds__(256) void pair_scalar(
    const float* __restrict__ ws,
    const float* __restrict__ w2a, const float* __restrict__ w2b,
    const float* __restrict__ w2c,
    const float* __restrict__ b2a, const float* __restrict__ b2b,
    const float* __restrict__ b2c,
    float* __restrict__ out) {
  const int b = blockIdx.z;
  const int i0 = blockIdx.y * 16;
  const int j0 = blockIdx.x * 16;
  const int tid = threadIdx.x;
  const int tx = tid & 15;   // j
  const int ty = tid >> 4;   // i
  const bool skip_span = (blockIdx.y < blockIdx.x);  // strictly upper tile

  __shared__ float Ls[16][129];
  __shared__ float Rst[128][17];   // transposed: [l][j]
  __shared__ float w2s[128];

  float acc0 = 0.f, acc1 = 0.f, acc2 = 0.f;
  const float* w2p[3] = {w2a, w2b, w2c};

#pragma unroll
  for (int h = 0; h < 3; ++h) {
    if (h == 0 && skip_span) continue;
    const float* Lb = ws + (h * 2) * SLOT + (b * Ssz + i0) * Lsz;
    const float* Rb = ws + (h * 2 + 1) * SLOT + (b * Ssz + j0) * Lsz;
    const float* w2 = w2p[h];
    float accl = 0.f;
    for (int lc = 0; lc < Lsz; lc += 128) {
      __syncthreads();
      {
        int rr = tid >> 4;
        int c = (tid & 15) * 8;
        float4 v0 = *(const float4*)(Lb + rr * Lsz + lc + c);
        float4 v1 = *(const float4*)(Lb + rr * Lsz + lc + c + 4);
        Ls[rr][c + 0] = v0.x; Ls[rr][c + 1] = v0.y;
        Ls[rr][c + 2] = v0.z; Ls[rr][c + 3] = v0.w;
        Ls[rr][c + 4] = v1.x; Ls[rr][c + 5] = v1.y;
        Ls[rr][c + 6] = v1.z; Ls[rr][c + 7] = v1.w;
        float4 u0 = *(const float4*)(Rb + rr * Lsz + lc + c);
        float4 u1 = *(const float4*)(Rb + rr * Lsz + lc + c + 4);
        Rst[c + 0][rr] = u0.x; Rst[c + 1][rr] = u0.y;
        Rst[c + 2][rr] = u0.z; Rst[c + 3][rr] = u0.w;
        Rst[c + 4][rr] = u1.x; Rst[c + 5][rr] = u1.y;
        Rst[c + 6][rr] = u1.z; Rst[c + 7][rr] = u1.w;
      }
      if (tid < 128) w2s[tid] = w2[lc + tid];
      __syncthreads();
#pragma unroll 16
      for (int l = 0; l < 128; ++l) {
        accl += fast_tanh(Ls[ty][l] + Rst[l][tx]) * w2s[l];
      }
    }
    if (h == 0) acc0 = accl;
    else if (h == 1) acc1 = accl;
    else acc2 = accl;
  }

  const int i = i0 + ty, j = j0 + tx;
  const int base = (b * Ssz + i) * Ssz + j;
  out[OUTMAT + base] = acc1 + b2b[0];
  out[2 * OUTMAT + base] = acc2 + b2c[0];
  if (!skip_span && i >= j) {
    float v = acc0 + b2a[0];
    out[(b * Ssz + i) * Ssz + j] = v;
    out[(b * Ssz + j) * Ssz + i] = v;
  }
}

// ---------------------------------------------------------------------------
// Kernel 2.5: transpose + bf16-convert label W2 [512l][50o] -> [64o][512l],
// zero-padded to o=64. Runs after pair_scalar; output lives in ws slot 0.
// ---------------------------------------------------------------------------
__global__ __launch_bounds__(256) void w2prep(const float* __restrict__ W2,
                                              unsigned short* __restrict__ o) {
  int idx = blockIdx.x * 256 + threadIdx.x;  // 64*512 total
  int oo = idx >> 9, k = idx & 511;
  float v = (oo < Rsz) ? W2[k * Rsz + oo] : 0.0f;
  o[oo * Lsz + k] = (unsigned short)f2bf(v);
}

// ---------------------------------------------------------------------------
// Kernel 3: label head via bf16 MFMA. One wg (4 waves) per (b,i).
// Wave w computes j-rows [32w,32w+32): 2 m-tiles x 4 n-tiles of 16x16x32
// MFMA, K=512. A-fragments (tanh(L+R)) are generated DIRECTLY in the MFMA
// A lane layout (A[m=lane&15][k=quad*8+idx]) from global reads — no LDS at
// all, so no bank conflicts and no LDS occupancy cap.
// ---------------------------------------------------------------------------
__global__ __launch_bounds__(256) void pair_label_mfma(
    const float* __restrict__ ws, const unsigned short* __restrict__ W2bfT,
    const float* __restrict__ b2, float* __restrict__ out) {
  const int b = blockIdx.y;
  const int i = blockIdx.x;
  const int tid = threadIdx.x;
  const int wave = tid >> 6;
  const int lane = tid & 63;
  const int lm = lane & 15;
  const int quad = lane >> 4;
  const int jb = wave * 32;

  const float* Lrow = ws + 6 * SLOT + (b * Ssz + i) * Lsz;
  const float* Rbase = ws + 7 * SLOT + (long)b * Ssz * Lsz;
  float* out3 = out + 3 * OUTMAT;

  f32x4 acc[2][4];
#pragma unroll
  for (int mt = 0; mt < 2; ++mt)
#pragma unroll
    for (int nt = 0; nt < 4; ++nt) {
      acc[mt][nt].x = 0.f; acc[mt][nt].y = 0.f;
      acc[mt][nt].z = 0.f; acc[mt][nt].w = 0.f;
    }

  for (int kc = 0; kc < Lsz; kc += 32) {
    const int k0 = kc + quad * 8;
    float4 lf0 = *(const float4*)(Lrow + k0);
    float4 lf1 = *(const float4*)(Lrow + k0 + 4);
    bf16x8 af[2];
#pragma unroll
    for (int mt = 0; mt < 2; ++mt) {
      const float* rp = Rbase + (jb + mt * 16 + lm) * Lsz + k0;
      float4 r0 = *(const float4*)rp;
      float4 r1 = *(const float4*)(rp + 4);
      bf16x8 a;
      a[0] = f2bf(fast_tanh(lf0.x + r0.x));
      a[1] = f2bf(fast_tanh(lf0.y + r0.y));
      a[2] = f2bf(fast_tanh(lf0.z + r0.z));
      a[3] = f2bf(fast_tanh(lf0.w + r0.w));
      a[4] = f2bf(fast_tanh(lf1.x + r1.x));
      a[5] = f2bf(fast_tanh(lf1.y + r1.y));
      a[6] = f2bf(fast_tanh(lf1.z + r1.z));
      a[7] = f2bf(fast_tanh(lf1.w + r1.w));
      af[mt] = a;
    }
    bf16x8 bfr[4];
#pragma unroll
    for (int nt = 0; nt < 4; ++nt)
      bfr[nt] = *(const bf16x8*)(W2bfT + (nt * 16 + lm) * Lsz + k0);
#pragma unroll
    for (int mt = 0; mt < 2; ++mt)
#pragma unroll
      for (int nt = 0; nt < 4; ++nt)
        acc[mt][nt] = __builtin_amdgcn_mfma_f32_16x16x32_bf16(
            af[mt], bfr[nt], acc[mt][nt], 0, 0, 0);
  }

  // epilogue: D layout col=lane&15 (o), row=quad*4+reg (j within 16-tile)
  float bias[4];
#pragma unroll
  for (int nt = 0; nt < 4; ++nt) {
    int o = nt * 16 + lm;
    bias[nt] = (o < Rsz) ? b2[o] : 0.0f;
  }
#pragma unroll
  for (int mt = 0; mt < 2; ++mt) {
#pragma unroll
    for (int nt = 0; nt < 4; ++nt) {
      int o = nt * 16 + lm;
      if (o >= Rsz) continue;
#pragma unroll
      for (int reg = 0; reg < 4; ++reg) {
        int j = jb + mt * 16 + quad * 4 + reg;
        long base = ((long)(b * Ssz + i) * Ssz + j) * Rsz;
        float v;
        if (reg == 0) v = acc[mt][nt].x;
        else if (reg == 1) v = acc[mt][nt].y;
        else if (reg == 2) v = acc[mt][nt].z;
        else v = acc[mt][nt].w;
        out3[base + o] = v + bias[nt];
      }
    }
  }
}

extern "C" void kernel_launch(void* const* d_in, const int* in_sizes, int n_in,
                              void* d_out, int out_size, void* d_ws,
                              size_t ws_size, hipStream_t stream) {
  (void)in_sizes; (void)n_in; (void)out_size; (void)ws_size;
  const float* x = (const float*)d_in[0];
  K1Args a;
  a.W1[0] = (const float*)d_in[1];  a.b1[0] = (const float*)d_in[2];
  a.W1[1] = (const float*)d_in[5];  a.b1[1] = (const float*)d_in[6];
  a.W1[2] = (const float*)d_in[9];  a.b1[2] = (const float*)d_in[10];
  a.W1[3] = (const float*)d_in[13]; a.b1[3] = (const float*)d_in[14];
  const float* w2a = (const float*)d_in[3];
  const float* b2a = (const float*)d_in[4];
  const float* w2b = (const float*)d_in[7];
  const float* b2b = (const float*)d_in[8];
  const float* w2c = (const float*)d_in[11];
  const float* b2c = (const float*)d_in[12];
  const float* W2l = (const float*)d_in[15];
  const float* b2l = (const float*)d_in[16];
  float* ws = (float*)d_ws;   // 8 slots of 1024x512 fp32 = 16 MB
  float* out = (float*)d_out;

  dim3 g1(Lsz / 64, Mrows / 64, 8);
  gemm_lr<<<g1, 256, 0, stream>>>(x, a, ws);
  dim3 g2(Ssz / 16, Ssz / 16, Bsz);
  pair_scalar<<<g2, 256, 0, stream>>>(ws, w2a, w2b, w2c, b2a, b2b, b2c, out);
  // W2bfT (64x512 bf16 = 64KB) goes into ws slot 0 — safe because the stream
  // serializes kernels and pair_scalar (the last reader of slot 0) is done.
  unsigned short* W2bfT = (unsigned short*)ws;
  w2prep<<<(64 * Lsz) / 256, 256, 0, stream>>>(W2l, W2bfT);
  dim3 g3(Ssz, Bsz);
  pair_label_mfma<<<g3, 256, 0, stream>>>(ws, W2bfT, b2l, out);
}